// Round 2
// baseline (815.242 us; speedup 1.0000x reference)
//
#include <hip/hip_runtime.h>
#include <stdint.h>

#define SEQ 8192
#define BATCH 16
#define DM 192
#define NROWS (BATCH*SEQ)   // 131072

typedef __attribute__((ext_vector_type(8))) short bf16x8;
typedef __attribute__((ext_vector_type(4))) float f32x4;

static __device__ __forceinline__ ushort f2bf(float f){
  uint u = __float_as_uint(f);
  u += 0x7fffu + ((u >> 16) & 1u);
  return (ushort)(u >> 16);
}
// load 8 consecutive f32, round to bf16x8 (A/B fragment)
static __device__ __forceinline__ bf16x8 cvt8(const float* p){
  float4 lo = *(const float4*)p;
  float4 hi = *(const float4*)(p + 4);
  bf16x8 t;
  t[0] = (short)f2bf(lo.x); t[1] = (short)f2bf(lo.y);
  t[2] = (short)f2bf(lo.z); t[3] = (short)f2bf(lo.w);
  t[4] = (short)f2bf(hi.x); t[5] = (short)f2bf(hi.y);
  t[6] = (short)f2bf(hi.z); t[7] = (short)f2bf(hi.w);
  return t;
}
static __device__ __forceinline__ void unpack2(uint u, float& lo, float& hi){
  lo = __uint_as_float(u << 16);
  hi = __uint_as_float(u & 0xffff0000u);
}

// -------- kernel 1: fused QKV projection (MFMA) + banded attention ------------
// 32 query rows per block (bisect: ONLY tile-size changed vs proven 64-row
// kernel). 3 m-tiles cover global rows m0-2 .. m0+45; k/v kept for rows
// m0-2..m0+33 (36 rows) in LDS bf16 (27.6 KB). q staged f32 in d_out, then
// overwritten in place by ctx (owner-exclusive per (row,head) after the
// workgroup barrier). acc[3][9]=108 regs -> natural VGPR ~150, 3 waves/SIMD.
__global__ __launch_bounds__(256) void qkv_attn(
    const float* __restrict__ x,
    const float* __restrict__ Wq, const float* __restrict__ bq,
    const float* __restrict__ Wk, const float* __restrict__ bk,
    const float* __restrict__ Wv, const float* __restrict__ bv,
    const float* __restrict__ mask0,
    float* ctxo)
{
  __shared__ ushort ks[36][192];   // rows m0-2 .. m0+33
  __shared__ ushort vs[36][192];

  const int tid  = threadIdx.x;
  const int wave = tid >> 6, lane = tid & 63;
  const int lm   = lane & 15, quad = lane >> 4;
  const int m0   = blockIdx.x * 32;
  const int wbase = wave * 144;   // 4 waves x 144 cols = 576 (q|k|v)

  // per-lane, per-nt weight row pointer + bias + proj (n never straddles 192)
  const float* wrow[9];
  float bias9[9];
  int proj9[9], cin9[9];
  #pragma unroll
  for (int nt = 0; nt < 9; nt++) {
    const int n = wbase + nt * 16 + lm;
    const int proj = n / DM;
    const int cin  = n - proj * DM;
    proj9[nt] = proj; cin9[nt] = cin;
    const float* w = (proj == 0) ? Wq : (proj == 1) ? Wk : Wv;
    wrow[nt] = w + (size_t)cin * DM;
    bias9[nt] = (proj == 0) ? bq[cin] : (proj == 1) ? bk[cin] : bv[cin];
  }

  f32x4 acc[3][9];
  #pragma unroll
  for (int a = 0; a < 3; a++)
    #pragma unroll
    for (int b = 0; b < 9; b++) acc[a][b] = (f32x4){0.f, 0.f, 0.f, 0.f};

  for (int kt = 0; kt < 6; kt++) {
    const int k0 = kt * 32 + quad * 8;
    bf16x8 af[3];
    #pragma unroll
    for (int mt = 0; mt < 3; mt++) {
      int g = m0 - 2 + mt * 16 + lm;          // global row (A m = lane&15)
      g = min(max(g, 0), NROWS - 1);          // clamp; garbage masked later
      af[mt] = cvt8(x + (size_t)g * DM + k0);
    }
    #pragma unroll
    for (int nt = 0; nt < 9; nt++) {
      bf16x8 bfm = cvt8(wrow[nt] + k0);
      #pragma unroll
      for (int mt = 0; mt < 3; mt++)
        acc[mt][nt] = __builtin_amdgcn_mfma_f32_16x16x32_bf16(af[mt], bfm, acc[mt][nt], 0, 0, 0);
    }
  }

  // epilogue. C/D: col=lane&15, row=quad*4+reg. q -> d_out f32; k,v -> LDS bf16
  const float qscale = 0.28867513459481287f;   // 1/sqrt(12); HF scales bias too
  #pragma unroll
  for (int nt = 0; nt < 9; nt++) {
    const int proj = proj9[nt], cin = cin9[nt];
    const float bsv = bias9[nt];
    #pragma unroll
    for (int mt = 0; mt < 3; mt++) {
      #pragma unroll
      for (int r = 0; r < 4; r++) {
        int lrow = mt * 16 + quad * 4 + r;     // 0..47 (global row m0-2+lrow)
        float vv = acc[mt][nt][r] + bsv;
        if (proj == 0) {
          if (lrow >= 2 && lrow < 34)
            ctxo[(size_t)(m0 + lrow - 2) * DM + cin] = vv * qscale;
        } else if (proj == 1) {
          if (lrow < 36) ks[lrow][cin] = f2bf(vv);
        } else {
          if (lrow < 36) vs[lrow][cin] = f2bf(vv);
        }
      }
    }
  }
  __syncthreads();

  // banded attention: 32 rows x 16 heads = 512 pairs, 2 per thread.
  // ks[0]/vs[0] = global row m0-2; neighbor of (m0+lr) at offset d-2 is lr+d.
  const float NEGF = -3.402823466e38f;
  #pragma unroll
  for (int it = 0; it < 2; it++) {
    const int pair = it * 256 + tid;
    const int h = pair & 15, lr = pair >> 4;   // lr 0..31
    const int row = m0 + lr;
    const int b = row >> 13, s = row & 8191;
    const float* mrow = mask0 + ((size_t)b << 13);

    float* qp = ctxo + (size_t)row * DM + h * 12;
    float4 q0 = *(const float4*)(qp);
    float4 q1 = *(const float4*)(qp + 4);
    float4 q2 = *(const float4*)(qp + 8);
    float qf[12] = {q0.x, q0.y, q0.z, q0.w, q1.x, q1.y, q1.z, q1.w,
                    q2.x, q2.y, q2.z, q2.w};

    float sc[5];
    #pragma unroll
    for (int d = 0; d < 5; d++) {
      int j = s + d - 2;
      if (j < 0 || j >= SEQ) { sc[d] = -INFINITY; continue; }
      float kf[12];
      const uint2* p = (const uint2*)&ks[lr + d][h * 12];
      uint2 t0 = p[0], t1 = p[1], t2 = p[2];
      unpack2(t0.x, kf[0], kf[1]);  unpack2(t0.y, kf[2], kf[3]);
      unpack2(t1.x, kf[4], kf[5]);  unpack2(t1.y, kf[6], kf[7]);
      unpack2(t2.x, kf[8], kf[9]);  unpack2(t2.y, kf[10], kf[11]);
      float dot = 0.f;
      #pragma unroll
      for (int t = 0; t < 12; t++) dot += qf[t] * kf[t];
      float fm = (mrow[j] != 0.0f) ? NEGF : 0.0f;
      sc[d] = dot + fm;
    }

    float mx = sc[0];
    #pragma unroll
    for (int d = 1; d < 5; d++) mx = fmaxf(mx, sc[d]);
    float e[5], sum = 0.f;
    #pragma unroll
    for (int d = 0; d < 5; d++) { e[d] = __expf(sc[d] - mx); sum += e[d]; }
    float inv = 1.0f / sum;
    const bool zrow = (mrow[s] < 0.0f);

    float cf[12];
    #pragma unroll
    for (int t = 0; t < 12; t++) cf[t] = 0.f;
    #pragma unroll
    for (int d = 0; d < 5; d++) {
      float p = zrow ? 0.f : e[d] * inv;     // e[d]=0 for out-of-range j
      float vf[12];
      const uint2* pv = (const uint2*)&vs[lr + d][h * 12];
      uint2 t0 = pv[0], t1 = pv[1], t2 = pv[2];
      unpack2(t0.x, vf[0], vf[1]);  unpack2(t0.y, vf[2], vf[3]);
      unpack2(t1.x, vf[4], vf[5]);  unpack2(t1.y, vf[6], vf[7]);
      unpack2(t2.x, vf[8], vf[9]);  unpack2(t2.y, vf[10], vf[11]);
      #pragma unroll
      for (int t = 0; t < 12; t++) cf[t] += p * vf[t];
    }

    *(float4*)(qp + 0) = make_float4(cf[0], cf[1], cf[2], cf[3]);
    *(float4*)(qp + 4) = make_float4(cf[4], cf[5], cf[6], cf[7]);
    *(float4*)(qp + 8) = make_float4(cf[8], cf[9], cf[10], cf[11]);
  }
}

// ---------------- kernel 2: out-proj + residual + LayerNorm (in-place) --------
// UNCHANGED from the proven 717us kernel. attn (f32 ctx) lives in the SAME
// buffer as out; per-block rows are disjoint and all ctx reads precede the
// barriers before the final store. Wo converted from f32 on the fly.
__global__ __launch_bounds__(256) void out_ln(
    const float* attn, const float* __restrict__ Wo,
    const float* __restrict__ bo, const float* __restrict__ x,
    const float* __restrict__ g, const float* __restrict__ beta,
    float* out)
{
  __shared__ float hs[64][200];
  __shared__ float red[64][8];
  __shared__ float stats[64][2];

  const int tid  = threadIdx.x;
  const int wave = tid >> 6, lane = tid & 63;
  const int lm   = lane & 15, quad = lane >> 4;
  const int m0   = blockIdx.x * 64;
  const int wbase = wave * 48;

  f32x4 acc[4][3];
  #pragma unroll
  for (int a = 0; a < 4; a++)
    #pragma unroll
    for (int b = 0; b < 3; b++) acc[a][b] = (f32x4){0.f, 0.f, 0.f, 0.f};

  for (int kt = 0; kt < 6; kt++) {
    const int k0 = kt * 32 + quad * 8;
    bf16x8 af[4];
    #pragma unroll
    for (int mt = 0; mt < 4; mt++)
      af[mt] = cvt8(attn + (size_t)(m0 + mt * 16 + lm) * DM + k0);
    #pragma unroll
    for (int nt = 0; nt < 3; nt++) {
      const int n = wbase + nt * 16 + lm;
      bf16x8 bfm = cvt8(Wo + (size_t)n * DM + k0);
      #pragma unroll
      for (int mt = 0; mt < 4; mt++)
        acc[mt][nt] = __builtin_amdgcn_mfma_f32_16x16x32_bf16(af[mt], bfm, acc[mt][nt], 0, 0, 0);
    }
  }

  // h = acc + bo + x  -> LDS
  #pragma unroll
  for (int nt = 0; nt < 3; nt++) {
    const int n = wbase + nt * 16 + lm;
    const float bsv = bo[n];
    #pragma unroll
    for (int mt = 0; mt < 4; mt++) {
      #pragma unroll
      for (int r = 0; r < 4; r++) {
        int rl = mt * 16 + quad * 4 + r;
        hs[rl][n] = acc[mt][nt][r] + bsv + x[(size_t)(m0 + rl) * DM + n];
      }
    }
  }
  __syncthreads();

  // partial reduce: 4 threads per row, 48 cols each
  {
    int row = tid >> 2, seg = tid & 3;
    float s = 0.f, s2 = 0.f;
    #pragma unroll
    for (int c = 0; c < 48; c++) {
      float t = hs[row][seg * 48 + c];
      s += t; s2 += t * t;
    }
    red[row][seg] = s;
    red[row][4 + seg] = s2;
  }
  __syncthreads();
  if (tid < 64) {
    float sum = red[tid][0] + red[tid][1] + red[tid][2] + red[tid][3];
    float sq  = red[tid][4] + red[tid][5] + red[tid][6] + red[tid][7];
    float mu  = sum * (1.f / 192.f);
    float var = sq * (1.f / 192.f) - mu * mu;
    stats[tid][0] = mu;
    stats[tid][1] = rsqrtf(var + 1e-12f);
  }
  __syncthreads();

  // normalize + store (float4)
  #pragma unroll
  for (int it = 0; it < 12; it++) {
    int idx = tid + it * 256;            // 0..3071
    int row = idx / 48, c4 = idx - row * 48;
    float4 hv = *(const float4*)&hs[row][c4 * 4];
    float mu = stats[row][0], rs = stats[row][1];
    float4 gg = *(const float4*)(g + c4 * 4);
    float4 bb = *(const float4*)(beta + c4 * 4);
    float4 o;
    o.x = (hv.x - mu) * rs * gg.x + bb.x;
    o.y = (hv.y - mu) * rs * gg.y + bb.y;
    o.z = (hv.z - mu) * rs * gg.z + bb.z;
    o.w = (hv.w - mu) * rs * gg.w + bb.w;
    *(float4*)(out + (size_t)(m0 + row) * DM + c4 * 4) = o;
  }
}

// ------------------------------- launcher ------------------------------------
extern "C" void kernel_launch(void* const* d_in, const int* in_sizes, int n_in,
                              void* d_out, int out_size, void* d_ws, size_t ws_size,
                              hipStream_t stream)
{
  const float* x    = (const float*)d_in[0];
  const float* mask0= (const float*)d_in[1];
  const float* Wq   = (const float*)d_in[2];
  const float* bq   = (const float*)d_in[3];
  const float* Wk   = (const float*)d_in[4];
  const float* bk   = (const float*)d_in[5];
  const float* Wv   = (const float*)d_in[6];
  const float* bv   = (const float*)d_in[7];
  const float* Wo   = (const float*)d_in[8];
  const float* bo   = (const float*)d_in[9];
  const float* lng  = (const float*)d_in[10];
  const float* lnb  = (const float*)d_in[11];
  float* out = (float*)d_out;

  qkv_attn<<<NROWS / 32, 256, 0, stream>>>(x, Wq, bq, Wk, bk, Wv, bv, mask0, out);
  out_ln<<<NROWS / 64, 256, 0, stream>>>(out, Wo, bo, x, lng, lnb, out);
}

// Round 3
// 643.567 us; speedup vs baseline: 1.2668x; 1.2668x over previous
//
#include <hip/hip_runtime.h>
#include <stdint.h>

#define SEQ 8192
#define BATCH 16
#define DM 192
#define NROWS (BATCH*SEQ)   // 131072

typedef __attribute__((ext_vector_type(8))) short bf16x8;
typedef __attribute__((ext_vector_type(4))) float f32x4;

static __device__ __forceinline__ ushort f2bf(float f){
  uint u = __float_as_uint(f);
  u += 0x7fffu + ((u >> 16) & 1u);
  return (ushort)(u >> 16);
}
// load 8 consecutive f32, round to bf16x8 (A/B fragment)
static __device__ __forceinline__ bf16x8 cvt8(const float* p){
  float4 lo = *(const float4*)p;
  float4 hi = *(const float4*)(p + 4);
  bf16x8 t;
  t[0] = (short)f2bf(lo.x); t[1] = (short)f2bf(lo.y);
  t[2] = (short)f2bf(lo.z); t[3] = (short)f2bf(lo.w);
  t[4] = (short)f2bf(hi.x); t[5] = (short)f2bf(hi.y);
  t[6] = (short)f2bf(hi.z); t[7] = (short)f2bf(hi.w);
  return t;
}
static __device__ __forceinline__ void unpack2(uint u, float& lo, float& hi){
  lo = __uint_as_float(u << 16);
  hi = __uint_as_float(u & 0xffff0000u);
}

// -------- kernel 1: fused QKV projection (MFMA) + banded attention ------------
// 64 query rows per block (proven structure). Delta vs 717us baseline: the
// A-panel (x rows m0-2..m0+65) is staged through LDS in thirds of 64 k-cols
// with COALESCED float4 loads, replacing the fully-fragmented strided lane
// loads (stride 768B) that all 4 waves redundantly issued. Mask row also
// staged in LDS. Weights remain strided (isolating the x-path this round).
// q staged f32 in d_out (proven path), then overwritten in place by ctx.
__global__ __launch_bounds__(256) void qkv_attn(
    const float* __restrict__ x,
    const float* __restrict__ Wq, const float* __restrict__ bq,
    const float* __restrict__ Wk, const float* __restrict__ bk,
    const float* __restrict__ Wv, const float* __restrict__ bv,
    const float* __restrict__ mask0,
    float* ctxo)
{
  __shared__ ushort ks[68][192];   // rows m0-2 .. m0+65
  __shared__ ushort vs[68][192];
  __shared__ ushort xs[68][72];    // staged x slice (64 k-cols), bf16, pad->72
  __shared__ float  ms[68];        // mask0 for global rows m0-2 .. m0+65

  const int tid  = threadIdx.x;
  const int wave = tid >> 6, lane = tid & 63;
  const int lm   = lane & 15, quad = lane >> 4;
  const int m0   = blockIdx.x * 64;
  const int wbase = wave * 144;   // 4 waves x 144 cols = 576 (q|k|v)

  // mask staging: batch-linear addressing is equivalent to per-batch rows
  // because out-of-batch neighbors are masked by the j-bounds check anyway.
  if (tid < 68) {
    int g = min(max(m0 - 2 + tid, 0), NROWS - 1);
    ms[tid] = mask0[g];
  }

  // per-lane, per-nt weight row pointer + bias + proj (n never straddles 192)
  const float* wrow[9];
  float bias9[9];
  int proj9[9], cin9[9];
  #pragma unroll
  for (int nt = 0; nt < 9; nt++) {
    const int n = wbase + nt * 16 + lm;
    const int proj = n / DM;
    const int cin  = n - proj * DM;
    proj9[nt] = proj; cin9[nt] = cin;
    const float* w = (proj == 0) ? Wq : (proj == 1) ? Wk : Wv;
    wrow[nt] = w + (size_t)cin * DM;
    bias9[nt] = (proj == 0) ? bq[cin] : (proj == 1) ? bk[cin] : bv[cin];
  }

  f32x4 acc[5][9];
  #pragma unroll
  for (int a = 0; a < 5; a++)
    #pragma unroll
    for (int b = 0; b < 9; b++) acc[a][b] = (f32x4){0.f, 0.f, 0.f, 0.f};

  for (int st = 0; st < 3; st++) {
    __syncthreads();               // previous stage's xs reads complete
    // stage xs: 68 rows x 64 cols f32 -> bf16; 1088 float4-chunks, coalesced
    for (int ch = tid; ch < 1088; ch += 256) {
      const int r = ch >> 4, c4 = (ch & 15) << 2;
      const int g = min(max(m0 - 2 + r, 0), NROWS - 1);
      float4 f = *(const float4*)(x + (size_t)g * DM + st * 64 + c4);
      ushort4 u;
      u.x = f2bf(f.x); u.y = f2bf(f.y); u.z = f2bf(f.z); u.w = f2bf(f.w);
      *(ushort4*)&xs[r][c4] = u;
    }
    __syncthreads();               // xs visible
    #pragma unroll
    for (int half = 0; half < 2; half++) {
      const int kt = st * 2 + half;
      const int k0 = kt * 32 + quad * 8;     // global k (weights)
      const int kl = half * 32 + quad * 8;   // local k in xs
      bf16x8 af[5];
      #pragma unroll
      for (int mt = 0; mt < 5; mt++) {
        int lrow = mt * 16 + lm;             // 0..79; rows >=68 are discarded
        lrow = min(lrow, 67);                // keep LDS read in-bounds
        af[mt] = *(const bf16x8*)&xs[lrow][kl];
      }
      #pragma unroll
      for (int nt = 0; nt < 9; nt++) {
        bf16x8 bfm = cvt8(wrow[nt] + k0);
        #pragma unroll
        for (int mt = 0; mt < 5; mt++)
          acc[mt][nt] = __builtin_amdgcn_mfma_f32_16x16x32_bf16(af[mt], bfm, acc[mt][nt], 0, 0, 0);
      }
    }
  }

  // epilogue. C/D: col=lane&15, row=quad*4+reg. q -> d_out f32; k,v -> LDS bf16
  const float qscale = 0.28867513459481287f;   // 1/sqrt(12); HF scales bias too
  #pragma unroll
  for (int nt = 0; nt < 9; nt++) {
    const int proj = proj9[nt], cin = cin9[nt];
    const float bsv = bias9[nt];
    #pragma unroll
    for (int mt = 0; mt < 5; mt++) {
      #pragma unroll
      for (int r = 0; r < 4; r++) {
        int lrow = mt * 16 + quad * 4 + r;     // 0..79 (global row m0-2+lrow)
        float vv = acc[mt][nt][r] + bsv;
        if (proj == 0) {
          if (lrow >= 2 && lrow < 66)
            ctxo[(size_t)(m0 + lrow - 2) * DM + cin] = vv * qscale;
        } else if (proj == 1) {
          if (lrow < 68) ks[lrow][cin] = f2bf(vv);
        } else {
          if (lrow < 68) vs[lrow][cin] = f2bf(vv);
        }
      }
    }
  }
  __syncthreads();

  // banded attention: 64 rows x 16 heads = 1024 pairs, 4 per thread.
  // ks[0]/vs[0] = global row m0-2; neighbor of (m0+lr) at offset d-2 is lr+d.
  const float NEGF = -3.402823466e38f;
  #pragma unroll
  for (int it = 0; it < 4; it++) {
    const int pair = it * 256 + tid;
    const int h = pair & 15, lr = pair >> 4;
    const int row = m0 + lr;
    const int s = row & 8191;

    float* qp = ctxo + (size_t)row * DM + h * 12;
    float4 q0 = *(const float4*)(qp);
    float4 q1 = *(const float4*)(qp + 4);
    float4 q2 = *(const float4*)(qp + 8);
    float qf[12] = {q0.x, q0.y, q0.z, q0.w, q1.x, q1.y, q1.z, q1.w,
                    q2.x, q2.y, q2.z, q2.w};

    float sc[5];
    #pragma unroll
    for (int d = 0; d < 5; d++) {
      int j = s + d - 2;
      if (j < 0 || j >= SEQ) { sc[d] = -INFINITY; continue; }
      float kf[12];
      const uint2* p = (const uint2*)&ks[lr + d][h * 12];
      uint2 t0 = p[0], t1 = p[1], t2 = p[2];
      unpack2(t0.x, kf[0], kf[1]);  unpack2(t0.y, kf[2], kf[3]);
      unpack2(t1.x, kf[4], kf[5]);  unpack2(t1.y, kf[6], kf[7]);
      unpack2(t2.x, kf[8], kf[9]);  unpack2(t2.y, kf[10], kf[11]);
      float dot = 0.f;
      #pragma unroll
      for (int t = 0; t < 12; t++) dot += qf[t] * kf[t];
      float fm = (ms[lr + d] != 0.0f) ? NEGF : 0.0f;
      sc[d] = dot + fm;
    }

    float mx = sc[0];
    #pragma unroll
    for (int d = 1; d < 5; d++) mx = fmaxf(mx, sc[d]);
    float e[5], sum = 0.f;
    #pragma unroll
    for (int d = 0; d < 5; d++) { e[d] = __expf(sc[d] - mx); sum += e[d]; }
    float inv = 1.0f / sum;
    const bool zrow = (ms[lr + 2] < 0.0f);

    float cf[12];
    #pragma unroll
    for (int t = 0; t < 12; t++) cf[t] = 0.f;
    #pragma unroll
    for (int d = 0; d < 5; d++) {
      float p = zrow ? 0.f : e[d] * inv;     // e[d]=0 for out-of-range j
      float vf[12];
      const uint2* pv = (const uint2*)&vs[lr + d][h * 12];
      uint2 t0 = pv[0], t1 = pv[1], t2 = pv[2];
      unpack2(t0.x, vf[0], vf[1]);  unpack2(t0.y, vf[2], vf[3]);
      unpack2(t1.x, vf[4], vf[5]);  unpack2(t1.y, vf[6], vf[7]);
      unpack2(t2.x, vf[8], vf[9]);  unpack2(t2.y, vf[10], vf[11]);
      #pragma unroll
      for (int t = 0; t < 12; t++) cf[t] += p * vf[t];
    }

    *(float4*)(qp + 0) = make_float4(cf[0], cf[1], cf[2], cf[3]);
    *(float4*)(qp + 4) = make_float4(cf[4], cf[5], cf[6], cf[7]);
    *(float4*)(qp + 8) = make_float4(cf[8], cf[9], cf[10], cf[11]);
  }
}

// ---------------- kernel 2: out-proj + residual + LayerNorm (in-place) --------
// UNCHANGED from the proven 717us kernel. attn (f32 ctx) lives in the SAME
// buffer as out; per-block rows are disjoint and all ctx reads precede the
// barriers before the final store. Wo converted from f32 on the fly.
__global__ __launch_bounds__(256) void out_ln(
    const float* attn, const float* __restrict__ Wo,
    const float* __restrict__ bo, const float* __restrict__ x,
    const float* __restrict__ g, const float* __restrict__ beta,
    float* out)
{
  __shared__ float hs[64][200];
  __shared__ float red[64][8];
  __shared__ float stats[64][2];

  const int tid  = threadIdx.x;
  const int wave = tid >> 6, lane = tid & 63;
  const int lm   = lane & 15, quad = lane >> 4;
  const int m0   = blockIdx.x * 64;
  const int wbase = wave * 48;

  f32x4 acc[4][3];
  #pragma unroll
  for (int a = 0; a < 4; a++)
    #pragma unroll
    for (int b = 0; b < 3; b++) acc[a][b] = (f32x4){0.f, 0.f, 0.f, 0.f};

  for (int kt = 0; kt < 6; kt++) {
    const int k0 = kt * 32 + quad * 8;
    bf16x8 af[4];
    #pragma unroll
    for (int mt = 0; mt < 4; mt++)
      af[mt] = cvt8(attn + (size_t)(m0 + mt * 16 + lm) * DM + k0);
    #pragma unroll
    for (int nt = 0; nt < 3; nt++) {
      const int n = wbase + nt * 16 + lm;
      bf16x8 bfm = cvt8(Wo + (size_t)n * DM + k0);
      #pragma unroll
      for (int mt = 0; mt < 4; mt++)
        acc[mt][nt] = __builtin_amdgcn_mfma_f32_16x16x32_bf16(af[mt], bfm, acc[mt][nt], 0, 0, 0);
    }
  }

  // h = acc + bo + x  -> LDS
  #pragma unroll
  for (int nt = 0; nt < 3; nt++) {
    const int n = wbase + nt * 16 + lm;
    const float bsv = bo[n];
    #pragma unroll
    for (int mt = 0; mt < 4; mt++) {
      #pragma unroll
      for (int r = 0; r < 4; r++) {
        int rl = mt * 16 + quad * 4 + r;
        hs[rl][n] = acc[mt][nt][r] + bsv + x[(size_t)(m0 + rl) * DM + n];
      }
    }
  }
  __syncthreads();

  // partial reduce: 4 threads per row, 48 cols each
  {
    int row = tid >> 2, seg = tid & 3;
    float s = 0.f, s2 = 0.f;
    #pragma unroll
    for (int c = 0; c < 48; c++) {
      float t = hs[row][seg * 48 + c];
      s += t; s2 += t * t;
    }
    red[row][seg] = s;
    red[row][4 + seg] = s2;
  }
  __syncthreads();
  if (tid < 64) {
    float sum = red[tid][0] + red[tid][1] + red[tid][2] + red[tid][3];
    float sq  = red[tid][4] + red[tid][5] + red[tid][6] + red[tid][7];
    float mu  = sum * (1.f / 192.f);
    float var = sq * (1.f / 192.f) - mu * mu;
    stats[tid][0] = mu;
    stats[tid][1] = rsqrtf(var + 1e-12f);
  }
  __syncthreads();

  // normalize + store (float4)
  #pragma unroll
  for (int it = 0; it < 12; it++) {
    int idx = tid + it * 256;            // 0..3071
    int row = idx / 48, c4 = idx - row * 48;
    float4 hv = *(const float4*)&hs[row][c4 * 4];
    float mu = stats[row][0], rs = stats[row][1];
    float4 gg = *(const float4*)(g + c4 * 4);
    float4 bb = *(const float4*)(beta + c4 * 4);
    float4 o;
    o.x = (hv.x - mu) * rs * gg.x + bb.x;
    o.y = (hv.y - mu) * rs * gg.y + bb.y;
    o.z = (hv.z - mu) * rs * gg.z + bb.z;
    o.w = (hv.w - mu) * rs * gg.w + bb.w;
    *(float4*)(out + (size_t)(m0 + row) * DM + c4 * 4) = o;
  }
}

// ------------------------------- launcher ------------------------------------
extern "C" void kernel_launch(void* const* d_in, const int* in_sizes, int n_in,
                              void* d_out, int out_size, void* d_ws, size_t ws_size,
                              hipStream_t stream)
{
  const float* x    = (const float*)d_in[0];
  const float* mask0= (const float*)d_in[1];
  const float* Wq   = (const float*)d_in[2];
  const float* bq   = (const float*)d_in[3];
  const float* Wk   = (const float*)d_in[4];
  const float* bk   = (const float*)d_in[5];
  const float* Wv   = (const float*)d_in[6];
  const float* bv   = (const float*)d_in[7];
  const float* Wo   = (const float*)d_in[8];
  const float* bo   = (const float*)d_in[9];
  const float* lng  = (const float*)d_in[10];
  const float* lnb  = (const float*)d_in[11];
  float* out = (float*)d_out;

  qkv_attn<<<NROWS / 64, 256, 0, stream>>>(x, Wq, bq, Wk, bk, Wv, bv, mask0, out);
  out_ln<<<NROWS / 64, 256, 0, stream>>>(out, Wo, bo, x, lng, lnb, out);
}

// Round 4
// 507.432 us; speedup vs baseline: 1.6066x; 1.2683x over previous
//
#include <hip/hip_runtime.h>
#include <stdint.h>

#define SEQ 8192
#define BATCH 16
#define DM 192
#define NROWS (BATCH*SEQ)   // 131072

// packed-weight workspace: 216 qkv frags + 72 wo frags, 1024 B each
#define WS_NEED 294912u
#define WO_OFF_U 110592    // ushort offset of Wo fragment region (216*512)

typedef __attribute__((ext_vector_type(8))) short bf16x8;
typedef __attribute__((ext_vector_type(4))) float f32x4;

static __device__ __forceinline__ ushort f2bf(float f){
  uint u = __float_as_uint(f);
  u += 0x7fffu + ((u >> 16) & 1u);
  return (ushort)(u >> 16);
}
// load 8 consecutive f32, round to bf16x8 (A/B fragment)
static __device__ __forceinline__ bf16x8 cvt8(const float* p){
  float4 lo = *(const float4*)p;
  float4 hi = *(const float4*)(p + 4);
  bf16x8 t;
  t[0] = (short)f2bf(lo.x); t[1] = (short)f2bf(lo.y);
  t[2] = (short)f2bf(lo.z); t[3] = (short)f2bf(lo.w);
  t[4] = (short)f2bf(hi.x); t[5] = (short)f2bf(hi.y);
  t[6] = (short)f2bf(hi.z); t[7] = (short)f2bf(hi.w);
  return t;
}
static __device__ __forceinline__ void unpack2(uint u, float& lo, float& hi){
  lo = __uint_as_float(u << 16);
  hi = __uint_as_float(u & 0xffff0000u);
}

// -------- pack kernel: weights f32 -> bf16, pre-swizzled to fragment order ----
// frag f<216: qkv, f=(w*9+nt)*6+kt ; lane reads W[cin][k0..k0+7].
// frag f>=216: Wo, fo=(w*3+nt)*6+kt.
// Layout: wp[f*512 + lane*8 .. +7]  (ushorts) -> main-kernel load is one
// coalesced global_load_dwordx4 per wave-instruction.
__global__ void pack_w(const float* __restrict__ Wq, const float* __restrict__ Wk,
                       const float* __restrict__ Wv, const float* __restrict__ Wo,
                       ushort* __restrict__ wp)
{
  const int f = blockIdx.x;          // 0..287
  const int lane = threadIdx.x;      // 0..63
  const int lm = lane & 15, quad = lane >> 4;
  const float* src;
  size_t dst;
  int kt;
  if (f < 216) {
    kt = f % 6; int t = f / 6; int nt = t % 9; int w = t / 9;
    int n = w * 144 + nt * 16 + lm;
    int proj = n / DM, cin = n - proj * DM;
    src = ((proj == 0) ? Wq : (proj == 1) ? Wk : Wv) + (size_t)cin * DM;
    dst = (size_t)f * 512 + (size_t)lane * 8;
  } else {
    int fo = f - 216;
    kt = fo % 6; int t = fo / 6; int nt = t % 3; int w = t / 3;
    int n = w * 48 + nt * 16 + lm;
    src = Wo + (size_t)n * DM;
    dst = (size_t)WO_OFF_U + (size_t)fo * 512 + (size_t)lane * 8;
  }
  const int k0 = kt * 32 + quad * 8;
  *(bf16x8*)(wp + dst) = cvt8(src + k0);
}

// -------- kernel 1: fused QKV projection (MFMA) + banded attention ------------
// 64 query rows per block. A-panel staged through LDS coalesced (R3, proven).
// PK=1: B-fragments loaded from pre-packed bf16 workspace (fully coalesced,
// no per-block cvt). PK=0: exact R3 fallback (on-the-fly strided cvt8).
template<int PK>
__global__ __launch_bounds__(256) void qkv_attn_t(
    const float* __restrict__ x,
    const float* __restrict__ Wq, const float* __restrict__ bq,
    const float* __restrict__ Wk, const float* __restrict__ bk,
    const float* __restrict__ Wv, const float* __restrict__ bv,
    const float* __restrict__ mask0,
    float* ctxo, const ushort* __restrict__ wp)
{
  __shared__ ushort ks[68][192];   // rows m0-2 .. m0+65
  __shared__ ushort vs[68][192];
  __shared__ ushort xs[68][72];    // staged x slice (64 k-cols), bf16, pad->72
  __shared__ float  ms[68];        // mask0 for global rows m0-2 .. m0+65

  const int tid  = threadIdx.x;
  const int wave = tid >> 6, lane = tid & 63;
  const int lm   = lane & 15, quad = lane >> 4;
  const int m0   = blockIdx.x * 64;
  const int wbase = wave * 144;   // 4 waves x 144 cols = 576 (q|k|v)

  if (tid < 68) {
    int g = min(max(m0 - 2 + tid, 0), NROWS - 1);
    ms[tid] = mask0[g];
  }

  // per-nt routing info (+ strided weight pointers only in fallback mode)
  const float* wrow[9];
  float bias9[9];
  int proj9[9], cin9[9];
  #pragma unroll
  for (int nt = 0; nt < 9; nt++) {
    const int n = wbase + nt * 16 + lm;
    const int proj = n / DM;
    const int cin  = n - proj * DM;
    proj9[nt] = proj; cin9[nt] = cin;
    bias9[nt] = (proj == 0) ? bq[cin] : (proj == 1) ? bk[cin] : bv[cin];
    if constexpr (!PK) {
      const float* w = (proj == 0) ? Wq : (proj == 1) ? Wk : Wv;
      wrow[nt] = w + (size_t)cin * DM;
    }
  }

  f32x4 acc[5][9];
  #pragma unroll
  for (int a = 0; a < 5; a++)
    #pragma unroll
    for (int b = 0; b < 9; b++) acc[a][b] = (f32x4){0.f, 0.f, 0.f, 0.f};

  for (int st = 0; st < 3; st++) {
    __syncthreads();               // previous stage's xs reads complete
    // stage xs: 68 rows x 64 cols f32 -> bf16; 1088 float4-chunks, coalesced
    for (int ch = tid; ch < 1088; ch += 256) {
      const int r = ch >> 4, c4 = (ch & 15) << 2;
      const int g = min(max(m0 - 2 + r, 0), NROWS - 1);
      float4 f = *(const float4*)(x + (size_t)g * DM + st * 64 + c4);
      ushort4 u;
      u.x = f2bf(f.x); u.y = f2bf(f.y); u.z = f2bf(f.z); u.w = f2bf(f.w);
      *(ushort4*)&xs[r][c4] = u;
    }
    __syncthreads();               // xs visible
    #pragma unroll
    for (int half = 0; half < 2; half++) {
      const int kt = st * 2 + half;
      const int k0 = kt * 32 + quad * 8;     // global k (weights)
      const int kl = half * 32 + quad * 8;   // local k in xs
      bf16x8 af[5];
      #pragma unroll
      for (int mt = 0; mt < 5; mt++) {
        int lrow = mt * 16 + lm;             // 0..79; rows >=68 are discarded
        lrow = min(lrow, 67);                // keep LDS read in-bounds
        af[mt] = *(const bf16x8*)&xs[lrow][kl];
      }
      #pragma unroll
      for (int nt = 0; nt < 9; nt++) {
        bf16x8 bfm;
        if constexpr (PK)
          bfm = *(const bf16x8*)(wp + ((size_t)((wave * 9 + nt) * 6 + kt)) * 512
                                    + (size_t)lane * 8);
        else
          bfm = cvt8(wrow[nt] + k0);
        #pragma unroll
        for (int mt = 0; mt < 5; mt++)
          acc[mt][nt] = __builtin_amdgcn_mfma_f32_16x16x32_bf16(af[mt], bfm, acc[mt][nt], 0, 0, 0);
      }
    }
  }

  // epilogue. C/D: col=lane&15, row=quad*4+reg. q -> d_out f32; k,v -> LDS bf16
  const float qscale = 0.28867513459481287f;   // 1/sqrt(12); HF scales bias too
  #pragma unroll
  for (int nt = 0; nt < 9; nt++) {
    const int proj = proj9[nt], cin = cin9[nt];
    const float bsv = bias9[nt];
    #pragma unroll
    for (int mt = 0; mt < 5; mt++) {
      #pragma unroll
      for (int r = 0; r < 4; r++) {
        int lrow = mt * 16 + quad * 4 + r;     // 0..79 (global row m0-2+lrow)
        float vv = acc[mt][nt][r] + bsv;
        if (proj == 0) {
          if (lrow >= 2 && lrow < 66)
            ctxo[(size_t)(m0 + lrow - 2) * DM + cin] = vv * qscale;
        } else if (proj == 1) {
          if (lrow < 68) ks[lrow][cin] = f2bf(vv);
        } else {
          if (lrow < 68) vs[lrow][cin] = f2bf(vv);
        }
      }
    }
  }
  __syncthreads();

  // banded attention: 64 rows x 16 heads = 1024 pairs, 4 per thread.
  // ks[0]/vs[0] = global row m0-2; neighbor of (m0+lr) at offset d-2 is lr+d.
  const float NEGF = -3.402823466e38f;
  #pragma unroll
  for (int it = 0; it < 4; it++) {
    const int pair = it * 256 + tid;
    const int h = pair & 15, lr = pair >> 4;
    const int row = m0 + lr;
    const int s = row & 8191;

    float* qp = ctxo + (size_t)row * DM + h * 12;
    float4 q0 = *(const float4*)(qp);
    float4 q1 = *(const float4*)(qp + 4);
    float4 q2 = *(const float4*)(qp + 8);
    float qf[12] = {q0.x, q0.y, q0.z, q0.w, q1.x, q1.y, q1.z, q1.w,
                    q2.x, q2.y, q2.z, q2.w};

    float sc[5];
    #pragma unroll
    for (int d = 0; d < 5; d++) {
      int j = s + d - 2;
      if (j < 0 || j >= SEQ) { sc[d] = -INFINITY; continue; }
      float kf[12];
      const uint2* p = (const uint2*)&ks[lr + d][h * 12];
      uint2 t0 = p[0], t1 = p[1], t2 = p[2];
      unpack2(t0.x, kf[0], kf[1]);  unpack2(t0.y, kf[2], kf[3]);
      unpack2(t1.x, kf[4], kf[5]);  unpack2(t1.y, kf[6], kf[7]);
      unpack2(t2.x, kf[8], kf[9]);  unpack2(t2.y, kf[10], kf[11]);
      float dot = 0.f;
      #pragma unroll
      for (int t = 0; t < 12; t++) dot += qf[t] * kf[t];
      float fm = (ms[lr + d] != 0.0f) ? NEGF : 0.0f;
      sc[d] = dot + fm;
    }

    float mx = sc[0];
    #pragma unroll
    for (int d = 1; d < 5; d++) mx = fmaxf(mx, sc[d]);
    float e[5], sum = 0.f;
    #pragma unroll
    for (int d = 0; d < 5; d++) { e[d] = __expf(sc[d] - mx); sum += e[d]; }
    float inv = 1.0f / sum;
    const bool zrow = (ms[lr + 2] < 0.0f);

    float cf[12];
    #pragma unroll
    for (int t = 0; t < 12; t++) cf[t] = 0.f;
    #pragma unroll
    for (int d = 0; d < 5; d++) {
      float p = zrow ? 0.f : e[d] * inv;     // e[d]=0 for out-of-range j
      float vf[12];
      const uint2* pv = (const uint2*)&vs[lr + d][h * 12];
      uint2 t0 = pv[0], t1 = pv[1], t2 = pv[2];
      unpack2(t0.x, vf[0], vf[1]);  unpack2(t0.y, vf[2], vf[3]);
      unpack2(t1.x, vf[4], vf[5]);  unpack2(t1.y, vf[6], vf[7]);
      unpack2(t2.x, vf[8], vf[9]);  unpack2(t2.y, vf[10], vf[11]);
      #pragma unroll
      for (int t = 0; t < 12; t++) cf[t] += p * vf[t];
    }

    *(float4*)(qp + 0) = make_float4(cf[0], cf[1], cf[2], cf[3]);
    *(float4*)(qp + 4) = make_float4(cf[4], cf[5], cf[6], cf[7]);
    *(float4*)(qp + 8) = make_float4(cf[8], cf[9], cf[10], cf[11]);
  }
}

// ---------------- kernel 2: out-proj + residual + LayerNorm (in-place) --------
// PK=1: Wo fragments from packed workspace. attn (f32 ctx) lives in the SAME
// buffer as out; per-block rows are disjoint and all ctx reads precede the
// barriers before the final store.
template<int PK>
__global__ __launch_bounds__(256) void out_ln_t(
    const float* attn, const float* __restrict__ Wo,
    const float* __restrict__ bo, const float* __restrict__ x,
    const float* __restrict__ g, const float* __restrict__ beta,
    float* out, const ushort* __restrict__ wp)
{
  __shared__ float hs[64][200];
  __shared__ float red[64][8];
  __shared__ float stats[64][2];

  const int tid  = threadIdx.x;
  const int wave = tid >> 6, lane = tid & 63;
  const int lm   = lane & 15, quad = lane >> 4;
  const int m0   = blockIdx.x * 64;
  const int wbase = wave * 48;

  f32x4 acc[4][3];
  #pragma unroll
  for (int a = 0; a < 4; a++)
    #pragma unroll
    for (int b = 0; b < 3; b++) acc[a][b] = (f32x4){0.f, 0.f, 0.f, 0.f};

  for (int kt = 0; kt < 6; kt++) {
    const int k0 = kt * 32 + quad * 8;
    bf16x8 af[4];
    #pragma unroll
    for (int mt = 0; mt < 4; mt++)
      af[mt] = cvt8(attn + (size_t)(m0 + mt * 16 + lm) * DM + k0);
    #pragma unroll
    for (int nt = 0; nt < 3; nt++) {
      bf16x8 bfm;
      if constexpr (PK)
        bfm = *(const bf16x8*)(wp + WO_OFF_U
                                  + ((size_t)((wave * 3 + nt) * 6 + kt)) * 512
                                  + (size_t)lane * 8);
      else {
        const int n = wbase + nt * 16 + lm;
        bfm = cvt8(Wo + (size_t)n * DM + k0);
      }
      #pragma unroll
      for (int mt = 0; mt < 4; mt++)
        acc[mt][nt] = __builtin_amdgcn_mfma_f32_16x16x32_bf16(af[mt], bfm, acc[mt][nt], 0, 0, 0);
    }
  }

  // h = acc + bo + x  -> LDS
  #pragma unroll
  for (int nt = 0; nt < 3; nt++) {
    const int n = wbase + nt * 16 + lm;
    const float bsv = bo[n];
    #pragma unroll
    for (int mt = 0; mt < 4; mt++) {
      #pragma unroll
      for (int r = 0; r < 4; r++) {
        int rl = mt * 16 + quad * 4 + r;
        hs[rl][n] = acc[mt][nt][r] + bsv + x[(size_t)(m0 + rl) * DM + n];
      }
    }
  }
  __syncthreads();

  // partial reduce: 4 threads per row, 48 cols each
  {
    int row = tid >> 2, seg = tid & 3;
    float s = 0.f, s2 = 0.f;
    #pragma unroll
    for (int c = 0; c < 48; c++) {
      float t = hs[row][seg * 48 + c];
      s += t; s2 += t * t;
    }
    red[row][seg] = s;
    red[row][4 + seg] = s2;
  }
  __syncthreads();
  if (tid < 64) {
    float sum = red[tid][0] + red[tid][1] + red[tid][2] + red[tid][3];
    float sq  = red[tid][4] + red[tid][5] + red[tid][6] + red[tid][7];
    float mu  = sum * (1.f / 192.f);
    float var = sq * (1.f / 192.f) - mu * mu;
    stats[tid][0] = mu;
    stats[tid][1] = rsqrtf(var + 1e-12f);
  }
  __syncthreads();

  // normalize + store (float4)
  #pragma unroll
  for (int it = 0; it < 12; it++) {
    int idx = tid + it * 256;            // 0..3071
    int row = idx / 48, c4 = idx - row * 48;
    float4 hv = *(const float4*)&hs[row][c4 * 4];
    float mu = stats[row][0], rs = stats[row][1];
    float4 gg = *(const float4*)(g + c4 * 4);
    float4 bb = *(const float4*)(beta + c4 * 4);
    float4 o;
    o.x = (hv.x - mu) * rs * gg.x + bb.x;
    o.y = (hv.y - mu) * rs * gg.y + bb.y;
    o.z = (hv.z - mu) * rs * gg.z + bb.z;
    o.w = (hv.w - mu) * rs * gg.w + bb.w;
    *(float4*)(out + (size_t)(m0 + row) * DM + c4 * 4) = o;
  }
}

// ------------------------------- launcher ------------------------------------
extern "C" void kernel_launch(void* const* d_in, const int* in_sizes, int n_in,
                              void* d_out, int out_size, void* d_ws, size_t ws_size,
                              hipStream_t stream)
{
  const float* x    = (const float*)d_in[0];
  const float* mask0= (const float*)d_in[1];
  const float* Wq   = (const float*)d_in[2];
  const float* bq   = (const float*)d_in[3];
  const float* Wk   = (const float*)d_in[4];
  const float* bk   = (const float*)d_in[5];
  const float* Wv   = (const float*)d_in[6];
  const float* bv   = (const float*)d_in[7];
  const float* Wo   = (const float*)d_in[8];
  const float* bo   = (const float*)d_in[9];
  const float* lng  = (const float*)d_in[10];
  const float* lnb  = (const float*)d_in[11];
  float* out = (float*)d_out;

  if (d_ws != nullptr && ws_size >= (size_t)WS_NEED) {
    ushort* wp = (ushort*)d_ws;
    pack_w<<<288, 64, 0, stream>>>(Wq, Wk, Wv, Wo, wp);
    qkv_attn_t<1><<<NROWS / 64, 256, 0, stream>>>(x, Wq, bq, Wk, bk, Wv, bv, mask0, out, wp);
    out_ln_t<1><<<NROWS / 64, 256, 0, stream>>>(out, Wo, bo, x, lng, lnb, out, wp);
  } else {
    qkv_attn_t<0><<<NROWS / 64, 256, 0, stream>>>(x, Wq, bq, Wk, bk, Wv, bv, mask0, out, nullptr);
    out_ln_t<0><<<NROWS / 64, 256, 0, stream>>>(out, Wo, bo, x, lng, lnb, out, nullptr);
  }
}